// Round 7
// baseline (76.657 us; speedup 1.0000x reference)
//
#include <hip/hip_runtime.h>
#include <hip/hip_bf16.h>

// ---------------------------------------------------------------------------
// Adapter: LayerNorm(2048) -> down(64) -> ReLU -> up(2048), 16384 tokens fp32.
// LN folded into down-proj (x read once):
//   down[n] = rstd*( dot(wg[n],x) - mu*s[n] ) + c[n],  wg = bf16(w_down*gamma)
// R7 = R5 (best: 68us) + DEEPER PREFETCH everywhere:
//  - x: 8-slot circular reg stage, issued 4 chunks ahead (~3 iters ~ HBM lat)
//  - wg: 4-slot circular, issued 3 chunks ahead (~L2 lat)
//  - up: wup/b_up 4-slot circular, 3 iters ahead; first slots issued BEFORE
//    the tile barrier so L2 latency overlaps the barrier wait.
// Structure, layouts, barrier protocol identical to R5.
// ---------------------------------------------------------------------------

typedef __attribute__((ext_vector_type(8))) short short8;   // 8 x bf16
typedef __attribute__((ext_vector_type(4))) float f32x4;

#define D_MODEL 2048
#define BNECK   64
#define EPS     1e-5f
#define NCHUNK  32          // chunks of K=64 (256B per row)

__device__ inline short f2bf(float f) {                     // prep only
    unsigned int u = __builtin_bit_cast(unsigned int, f);
    unsigned int r = (u + 0x7fffu + ((u >> 16) & 1u)) >> 16; // RNE
    return (short)r;
}
__device__ inline float bf2f(short s) {
    unsigned int u = ((unsigned int)(unsigned short)s) << 16;
    return __builtin_bit_cast(float, u);
}
__device__ inline short hbf(float f) {                      // HW RNE cvt
    __hip_bfloat16 h = __float2bfloat16(f);
    return __builtin_bit_cast(short, h);
}

// ---------------------------------------------------------------------------
// Prep. wg_perm slot = (n>>4)*64 + (k>>5): per-wave contiguous 64KB stream.
// Within slot: lane l = ((k>>3)&3)*16 + (n&15), elem e = k&7.
// wup_perm: slot (b16*2+h): lane l -> (d=b16*16+(l&15), kn=h*32+(l>>4)*8+e).
// s[n] = sum_k bf16(wg), c[n] = w_down[n,:].beta + b_down[n].
// ---------------------------------------------------------------------------
__global__ __launch_bounds__(256) void prep_kernel(
    const float* __restrict__ w_down, const float* __restrict__ gamma,
    const float* __restrict__ beta,   const float* __restrict__ b_down,
    const float* __restrict__ w_up,
    short* __restrict__ wg_perm, short* __restrict__ wup_perm,
    float* __restrict__ s_out, float* __restrict__ c_out)
{
    __shared__ float rs[4], rc[4];
    int b = blockIdx.x;
    if (b < BNECK) {
        int n = b, nf = n >> 4;
        float ps = 0.f, pc = 0.f;
        for (int d = threadIdx.x; d < D_MODEL; d += 256) {
            float wv = w_down[n * D_MODEL + d];
            short h  = f2bf(wv * gamma[d]);
            int t = d >> 5, kg = (d >> 3) & 3, e = d & 7;
            int l = kg * 16 + (n & 15);
            wg_perm[(size_t)((nf * 64 + t) * 64 + l) * 8 + e] = h;
            ps += bf2f(h);
            pc  = fmaf(wv, beta[d], pc);
        }
        for (int o = 32; o > 0; o >>= 1) {
            ps += __shfl_down(ps, o, 64);
            pc += __shfl_down(pc, o, 64);
        }
        int wid = threadIdx.x >> 6, lane = threadIdx.x & 63;
        if (lane == 0) { rs[wid] = ps; rc[wid] = pc; }
        __syncthreads();
        if (threadIdx.x == 0) {
            s_out[n] = rs[0] + rs[1] + rs[2] + rs[3];
            c_out[n] = rc[0] + rc[1] + rc[2] + rc[3] + b_down[n];
        }
    } else {
        for (int j = (b - BNECK) * 256 + threadIdx.x; j < D_MODEL * BNECK;
             j += 64 * 256) {
            int d = j >> 6, kn = j & 63;
            int b16 = d >> 4, h2 = kn >> 5, e = kn & 7;
            int l = ((kn >> 3) & 3) * 16 + (d & 15);
            wup_perm[(size_t)((b16 * 2 + h2) * 64 + l) * 8 + e] = f2bf(w_up[j]);
        }
    }
}

// ---------------------------------------------------------------------------
// Main kernel. 1024 blocks x 256 threads; block owns 16 tokens; waves n-split.
// ---------------------------------------------------------------------------
__global__ __launch_bounds__(256, 4) void adapter_kernel(
    const float* __restrict__ x,    const float* __restrict__ b_up,
    const short* __restrict__ wg_perm, const short* __restrict__ wup_perm,
    const float* __restrict__ s_v,  const float* __restrict__ c_v,
    float* __restrict__ out)
{
    __shared__ __align__(16) char xbuf[2][4096];   // shared dbuf: 16 rows x 256B
    __shared__ __align__(16) char tilebuf[2048];   // 16x64 bf16, swizzled
    __shared__ float stats2[16][2];                // per-token (mu, rstd)

    const int wid  = threadIdx.x >> 6;
    const int lane = threadIdx.x & 63;
    const int r    = lane & 15;          // frag row/col index
    const int g    = lane >> 4;          // k-group
    const int row0 = blockIdx.x * 16;
    const int swz  = (r & 7) << 4;

    // ---- cooperative staging: wave wid owns rows [wid*4, wid*4+4) ---------
    const int srow = wid * 4 + g;                  // this lane's staged row
    const int scol = r * 16;                       // byte col within 256B chunk
    const char* xsrc = (const char*)x
        + ((size_t)(row0 + srow) * D_MODEL) * 4 + scol;
    char* const swdst = &xbuf[0][0] + srow * 256 + (scol ^ ((srow & 7) << 4));

    const short* wbase = wg_perm + (size_t)(wid * 64) * 512 + lane * 8;

    f32x4  xr[8];            // register-staged x chunks (4 ahead)
    short8 wb[4][2];         // weight frags (3 ahead)
    f32x4  acc = (f32x4){0.f, 0.f, 0.f, 0.f};
    float  ssum = 0.f, ssq = 0.f;

    auto LDX = [&](int c) { return *(const f32x4*)(xsrc + c * 256); };
    auto LDW = [&](int c, short8* w) {
        w[0] = *(const short8*)(wbase + (size_t)(c * 2 + 0) * 512);
        w[1] = *(const short8*)(wbase + (size_t)(c * 2 + 1) * 512);
    };
    auto STATS_WRITE = [&](int c, const f32x4& v) {   // stats + publish to LDS
        ssum += (v.x + v.y) + (v.z + v.w);
        ssq = fmaf(v.x, v.x, ssq); ssq = fmaf(v.y, v.y, ssq);
        ssq = fmaf(v.z, v.z, ssq); ssq = fmaf(v.w, v.w, ssq);
        *(f32x4*)(swdst + (size_t)(c & 1) * 4096) = v;    // ds_write_b128
    };

    // prologue: x 4 chunks in flight, weights 3 chunks ahead
    xr[0] = LDX(0); xr[1] = LDX(1); xr[2] = LDX(2); xr[3] = LDX(3);
    LDW(0, wb[0]); LDW(1, wb[1]); LDW(2, wb[2]);
    STATS_WRITE(0, xr[0]);

#pragma unroll
    for (int c = 0; c < NCHUNK; ++c) {
        if (c + 4 < NCHUNK) xr[(c + 4) & 7] = LDX(c + 4);
        if (c + 3 < NCHUNK) LDW(c + 3, wb[(c + 3) & 3]);
        // publish writes of chunk c; certify reads of buf[(c+1)&1] finished
        asm volatile("s_waitcnt lgkmcnt(0)\n\ts_barrier" ::: "memory");
        if (c + 1 < NCHUNK) STATS_WRITE(c + 1, xr[(c + 1) & 7]);

        const char* bp = &xbuf[c & 1][0];
        const short8* w = wb[c & 3];
#pragma unroll
        for (int kb = 0; kb < 2; ++kb) {
            int cb = kb * 128 + g * 32;
            f32x4 xa = *(const f32x4*)(bp + r * 256 + ( cb        ^ swz));
            f32x4 xb = *(const f32x4*)(bp + r * 256 + ((cb + 16)  ^ swz));
            short8 af;
            af[0] = hbf(xa.x); af[1] = hbf(xa.y);
            af[2] = hbf(xa.z); af[3] = hbf(xa.w);
            af[4] = hbf(xb.x); af[5] = hbf(xb.y);
            af[6] = hbf(xb.z); af[7] = hbf(xb.w);
            acc = __builtin_amdgcn_mfma_f32_16x16x32_bf16(af, w[kb], acc, 0, 0, 0);
        }
    }

    // ---- LN stats for this wave's 4 staged rows (reduce over 16 lanes) ----
#pragma unroll
    for (int m = 1; m < 16; m <<= 1) {
        ssum += __shfl_xor(ssum, m, 64);
        ssq  += __shfl_xor(ssq , m, 64);
    }
    float mu   = ssum * (1.f / D_MODEL);
    float rstd = rsqrtf(ssq * (1.f / D_MODEL) - mu * mu + EPS);
    if (r == 0) { stats2[srow][0] = mu; stats2[srow][1] = rstd; }
    __syncthreads();

    // ---- fix-up + ReLU: wave owns n = wid*16 + r, tokens m = g*4+reg ------
    {
        int   n  = wid * 16 + r;
        float sn = s_v[n], cn = c_v[n];
#pragma unroll
        for (int reg = 0; reg < 4; ++reg) {
            int   m = g * 4 + reg;
            float v = fmaf(stats2[m][1], acc[reg] - stats2[m][0] * sn, cn);
            v = fmaxf(v, 0.f);
            *(short*)(tilebuf + ((m * 128 + n * 2) ^ ((m & 7) << 4))) = hbf(v);
        }
    }

    // ---- up-GEMM weight prologue BEFORE the barrier (L2 lat overlaps it) --
    const short* wupl = wup_perm + lane * 8;
    short8 ua[4], ub[4];
    f32x4  bu4[4];
#pragma unroll
    for (int p = 0; p < 3; ++p) {
        int b16 = wid * 32 + p;
        ua[p] = *(const short8*)(wupl + (size_t)(b16 * 2 + 0) * 512);
        ub[p] = *(const short8*)(wupl + (size_t)(b16 * 2 + 1) * 512);
        bu4[p] = *(const f32x4*)(b_up + b16 * 16 + g * 4);
    }
    __syncthreads();

    // ---- up-GEMM (A = w_up fragment-major, B = down^T), 4-slot pipeline ---
    short8 bd0 = *(const short8*)(tilebuf + ((r * 128 +  0 + g * 16) ^ swz));
    short8 bd1 = *(const short8*)(tilebuf + ((r * 128 + 64 + g * 16) ^ swz));

    float* outr = out + (size_t)(row0 + r) * D_MODEL;

#pragma unroll
    for (int i = 0; i < 32; ++i) {
        int cur = i & 3;
        if (i + 3 < 32) {
            int b16 = wid * 32 + i + 3;
            int nxt = (i + 3) & 3;
            ua[nxt] = *(const short8*)(wupl + (size_t)(b16 * 2 + 0) * 512);
            ub[nxt] = *(const short8*)(wupl + (size_t)(b16 * 2 + 1) * 512);
            bu4[nxt] = *(const f32x4*)(b_up + b16 * 16 + g * 4);
        }
        f32x4 o = (f32x4){0.f, 0.f, 0.f, 0.f};
        o = __builtin_amdgcn_mfma_f32_16x16x32_bf16(ua[cur], bd0, o, 0, 0, 0);
        o = __builtin_amdgcn_mfma_f32_16x16x32_bf16(ub[cur], bd1, o, 0, 0, 0);
        int dbase = (wid * 32 + i) * 16;
        *(f32x4*)(outr + dbase + g * 4) = o + bu4[cur];
    }
}

extern "C" void kernel_launch(void* const* d_in, const int* in_sizes, int n_in,
                              void* d_out, int out_size, void* d_ws, size_t ws_size,
                              hipStream_t stream) {
    const float* x      = (const float*)d_in[0];
    const float* gamma  = (const float*)d_in[1];
    const float* beta   = (const float*)d_in[2];
    const float* w_down = (const float*)d_in[3];
    const float* b_down = (const float*)d_in[4];
    const float* w_up   = (const float*)d_in[5];
    const float* b_up   = (const float*)d_in[6];
    float* out = (float*)d_out;

    char* ws = (char*)d_ws;
    short* wg_perm  = (short*)ws;                 // 256 KB
    short* wup_perm = (short*)(ws + 262144);      // 256 KB
    float* s_v  = (float*)(ws + 524288);          // 256 B
    float* c_v  = (float*)(ws + 524544);          // 256 B

    prep_kernel<<<128, 256, 0, stream>>>(w_down, gamma, beta, b_down, w_up,
                                         wg_perm, wup_perm, s_v, c_v);
    adapter_kernel<<<1024, 256, 0, stream>>>(x, b_up, wg_perm, wup_perm,
                                             s_v, c_v, out);
}

// Round 8
// 75.621 us; speedup vs baseline: 1.0137x; 1.0137x over previous
//
#include <hip/hip_runtime.h>
#include <hip/hip_bf16.h>

// ---------------------------------------------------------------------------
// Adapter: LayerNorm(2048) -> down(64) -> ReLU -> up(2048), 16384 tokens fp32.
// LN folded into down-proj (x read once):
//   down[n] = rstd*( dot(wg[n],x) - mu*s[n] ) + c[n],  wg = bf16(w_down*gamma)
// R8: stage big, sync rarely. Block = 16 tokens, 4 waves (n-split).
//  - x staged as bf16 in LDS in TWO 16x1024 halves (32KB buffer), coalesced
//    f32x4 loads + one cvt pass + 2D XOR swizzle; stats in fp32 from regs.
//  - down K-loop is BARRIER-FREE: per step 1 ds_read_b128 + 1 coalesced
//    1KB weight load + 1 MFMA; dual accumulators; compiler pipelines.
//  - 5 barriers per block total (was 34). LDS 34KB -> 4 blocks/CU.
// ---------------------------------------------------------------------------

typedef __attribute__((ext_vector_type(8))) short short8;   // 8 x bf16
typedef __attribute__((ext_vector_type(4))) float f32x4;

#define D_MODEL 2048
#define BNECK   64
#define EPS     1e-5f

__device__ inline short f2bf(float f) {                     // prep only
    unsigned int u = __builtin_bit_cast(unsigned int, f);
    unsigned int r = (u + 0x7fffu + ((u >> 16) & 1u)) >> 16; // RNE
    return (short)r;
}
__device__ inline float bf2f(short s) {
    unsigned int u = ((unsigned int)(unsigned short)s) << 16;
    return __builtin_bit_cast(float, u);
}
__device__ inline short hbf(float f) {                      // HW RNE cvt
    __hip_bfloat16 h = __float2bfloat16(f);
    return __builtin_bit_cast(short, h);
}

// ---------------------------------------------------------------------------
// Prep. wg_perm slot = (n>>4)*64 + (k>>5): per-wave contiguous 64KB stream.
// Within slot: lane l = ((k>>3)&3)*16 + (n&15), elem e = k&7.
// wup_perm: slot (b16*2+h): lane l -> (d=b16*16+(l&15), kn=h*32+(l>>4)*8+e).
// s[n] = sum_k bf16(wg), c[n] = w_down[n,:].beta + b_down[n].
// ---------------------------------------------------------------------------
__global__ __launch_bounds__(256) void prep_kernel(
    const float* __restrict__ w_down, const float* __restrict__ gamma,
    const float* __restrict__ beta,   const float* __restrict__ b_down,
    const float* __restrict__ w_up,
    short* __restrict__ wg_perm, short* __restrict__ wup_perm,
    float* __restrict__ s_out, float* __restrict__ c_out)
{
    __shared__ float rs[4], rc[4];
    int b = blockIdx.x;
    if (b < BNECK) {
        int n = b, nf = n >> 4;
        float ps = 0.f, pc = 0.f;
        for (int d = threadIdx.x; d < D_MODEL; d += 256) {
            float wv = w_down[n * D_MODEL + d];
            short h  = f2bf(wv * gamma[d]);
            int t = d >> 5, kg = (d >> 3) & 3, e = d & 7;
            int l = kg * 16 + (n & 15);
            wg_perm[(size_t)((nf * 64 + t) * 64 + l) * 8 + e] = h;
            ps += bf2f(h);
            pc  = fmaf(wv, beta[d], pc);
        }
        for (int o = 32; o > 0; o >>= 1) {
            ps += __shfl_down(ps, o, 64);
            pc += __shfl_down(pc, o, 64);
        }
        int wid = threadIdx.x >> 6, lane = threadIdx.x & 63;
        if (lane == 0) { rs[wid] = ps; rc[wid] = pc; }
        __syncthreads();
        if (threadIdx.x == 0) {
            s_out[n] = rs[0] + rs[1] + rs[2] + rs[3];
            c_out[n] = rc[0] + rc[1] + rc[2] + rc[3] + b_down[n];
        }
    } else {
        for (int j = (b - BNECK) * 256 + threadIdx.x; j < D_MODEL * BNECK;
             j += 64 * 256) {
            int d = j >> 6, kn = j & 63;
            int b16 = d >> 4, h2 = kn >> 5, e = kn & 7;
            int l = ((kn >> 3) & 3) * 16 + (d & 15);
            wup_perm[(size_t)((b16 * 2 + h2) * 64 + l) * 8 + e] = f2bf(w_up[j]);
        }
    }
}

// ---------------------------------------------------------------------------
// Main kernel. 1024 blocks x 256 threads; block owns 16 tokens; waves n-split.
// ---------------------------------------------------------------------------
__global__ __launch_bounds__(256, 4) void adapter_kernel(
    const float* __restrict__ x,    const float* __restrict__ b_up,
    const short* __restrict__ wg_perm, const short* __restrict__ wup_perm,
    const float* __restrict__ s_v,  const float* __restrict__ c_v,
    float* __restrict__ out)
{
    __shared__ __align__(16) short xlds[16 * 1024];   // 32KB: 16 rows x 1024 bf16
    __shared__ __align__(16) char tilebuf[2048];      // 16x64 bf16, swizzled
    __shared__ float stats2[16][2];                   // per-token (mu, rstd)

    const int tid  = threadIdx.x;
    const int wid  = tid >> 6;
    const int lane = tid & 63;
    const int r    = lane & 15;          // frag row/col index
    const int g    = lane >> 4;          // k-group
    const int row0 = blockIdx.x * 16;
    const int swz  = (r & 7) << 4;       // tilebuf swizzle
    char* const ldsb = (char*)xlds;

    // ---- staging assignment: row = tid>>4, 64-f32 chunk sj = tid&15 -------
    const int srow = tid >> 4, sj = tid & 15;
    const float* xsrc = x + (size_t)(row0 + srow) * D_MODEL + sj * 64;
    const int wbyte0 = srow * 2048 + sj * 128;            // + (i*16 ^ wswz)
    const int wswz   = ((srow ^ (sj >> 1)) & 7) << 4;     // 2D XOR swizzle

    float ssum = 0.f, ssq = 0.f;

    // stage one 16x1024 half: 16 coalesced f32x4 loads, fp32 stats, cvt, write
    auto STAGE_HALF = [&](int half) {
        f32x4 v[16];
#pragma unroll
        for (int q = 0; q < 16; ++q)
            v[q] = *(const f32x4*)(xsrc + half * 1024 + q * 4);
#pragma unroll
        for (int q = 0; q < 16; ++q) {
            ssum += (v[q].x + v[q].y) + (v[q].z + v[q].w);
            ssq = fmaf(v[q].x, v[q].x, ssq); ssq = fmaf(v[q].y, v[q].y, ssq);
            ssq = fmaf(v[q].z, v[q].z, ssq); ssq = fmaf(v[q].w, v[q].w, ssq);
        }
#pragma unroll
        for (int i = 0; i < 8; ++i) {
            const f32x4 a = v[2 * i], b = v[2 * i + 1];
            short8 u;
            u[0] = hbf(a.x); u[1] = hbf(a.y); u[2] = hbf(a.z); u[3] = hbf(a.w);
            u[4] = hbf(b.x); u[5] = hbf(b.y); u[6] = hbf(b.z); u[7] = hbf(b.w);
            *(short8*)(ldsb + wbyte0 + ((i * 16) ^ wswz)) = u;
        }
    };

    const short* wbase = wg_perm + (size_t)(wid * 64) * 512 + lane * 8;
    f32x4 accA = (f32x4){0.f, 0.f, 0.f, 0.f};
    f32x4 accB = (f32x4){0.f, 0.f, 0.f, 0.f};

    // barrier-free 32-step K-half: ds_read_b128 + 1KB weight load + MFMA
    auto COMPUTE_HALF = [&](int half) {
#pragma unroll 8
        for (int s = 0; s < 32; ++s) {
            int cb = s * 64 + g * 16;
            int ra = r * 2048 + (cb ^ (((r ^ (s >> 2)) & 7) << 4));
            short8 af = *(const short8*)(ldsb + ra);
            short8 w  = *(const short8*)(wbase + (size_t)(half * 32 + s) * 512);
            if (s & 1)
                accB = __builtin_amdgcn_mfma_f32_16x16x32_bf16(af, w, accB, 0, 0, 0);
            else
                accA = __builtin_amdgcn_mfma_f32_16x16x32_bf16(af, w, accA, 0, 0, 0);
        }
    };

    STAGE_HALF(0);
    __syncthreads();                      // (1) half-0 tile ready
    COMPUTE_HALF(0);
    __syncthreads();                      // (2) all done reading half-0
    STAGE_HALF(1);

    // ---- LN stats: 16 threads per row (consecutive lanes) -----------------
#pragma unroll
    for (int m = 1; m < 16; m <<= 1) {
        ssum += __shfl_xor(ssum, m, 64);
        ssq  += __shfl_xor(ssq , m, 64);
    }
    float mu   = ssum * (1.f / D_MODEL);
    float rstd = rsqrtf(ssq * (1.f / D_MODEL) - mu * mu + EPS);
    if ((tid & 15) == 0) { stats2[srow][0] = mu; stats2[srow][1] = rstd; }
    __syncthreads();                      // (3) half-1 tile + stats ready
    COMPUTE_HALF(1);

    f32x4 acc = accA + accB;

    // ---- fix-up + ReLU: wave owns n = wid*16 + r, tokens m = g*4+reg ------
    {
        int   n  = wid * 16 + r;
        float sn = s_v[n], cn = c_v[n];
#pragma unroll
        for (int reg = 0; reg < 4; ++reg) {
            int   m = g * 4 + reg;
            float v = fmaf(stats2[m][1], acc[reg] - stats2[m][0] * sn, cn);
            v = fmaxf(v, 0.f);
            *(short*)(tilebuf + ((m * 128 + n * 2) ^ ((m & 7) << 4))) = hbf(v);
        }
    }
    __syncthreads();                      // (4) down tile ready

    // ---- up-GEMM (A = w_up fragment-major, B = down^T), R5 verbatim -------
    short8 bd0 = *(const short8*)(tilebuf + ((r * 128 +  0 + g * 16) ^ swz));
    short8 bd1 = *(const short8*)(tilebuf + ((r * 128 + 64 + g * 16) ^ swz));

    const short* wupl = wup_perm + lane * 8;
    float* outr = out + (size_t)(row0 + r) * D_MODEL;

    short8 ua[2], ub[2];
    {
        int b16 = wid * 32;
        ua[0] = *(const short8*)(wupl + (size_t)(b16 * 2 + 0) * 512);
        ub[0] = *(const short8*)(wupl + (size_t)(b16 * 2 + 1) * 512);
    }
#pragma unroll
    for (int i = 0; i < 32; ++i) {
        int cur = i & 1;
        if (i < 31) {
            int b16 = wid * 32 + i + 1;
            ua[cur ^ 1] = *(const short8*)(wupl + (size_t)(b16 * 2 + 0) * 512);
            ub[cur ^ 1] = *(const short8*)(wupl + (size_t)(b16 * 2 + 1) * 512);
        }
        f32x4 o = (f32x4){0.f, 0.f, 0.f, 0.f};
        o = __builtin_amdgcn_mfma_f32_16x16x32_bf16(ua[cur], bd0, o, 0, 0, 0);
        o = __builtin_amdgcn_mfma_f32_16x16x32_bf16(ub[cur], bd1, o, 0, 0, 0);
        int dbase = (wid * 32 + i) * 16;
        f32x4 bu = *(const f32x4*)(b_up + dbase + g * 4);
        *(f32x4*)(outr + dbase + g * 4) = o + bu;
    }
}

extern "C" void kernel_launch(void* const* d_in, const int* in_sizes, int n_in,
                              void* d_out, int out_size, void* d_ws, size_t ws_size,
                              hipStream_t stream) {
    const float* x      = (const float*)d_in[0];
    const float* gamma  = (const float*)d_in[1];
    const float* beta   = (const float*)d_in[2];
    const float* w_down = (const float*)d_in[3];
    const float* b_down = (const float*)d_in[4];
    const float* w_up   = (const float*)d_in[5];
    const float* b_up   = (const float*)d_in[6];
    float* out = (float*)d_out;

    char* ws = (char*)d_ws;
    short* wg_perm  = (short*)ws;                 // 256 KB
    short* wup_perm = (short*)(ws + 262144);      // 256 KB
    float* s_v  = (float*)(ws + 524288);          // 256 B
    float* c_v  = (float*)(ws + 524544);          // 256 B

    prep_kernel<<<128, 256, 0, stream>>>(w_down, gamma, beta, b_down, w_up,
                                         wg_perm, wup_perm, s_v, c_v);
    adapter_kernel<<<1024, 256, 0, stream>>>(x, b_up, wg_perm, wup_perm,
                                             s_v, c_v, out);
}